// Round 5
// baseline (218.002 us; speedup 1.0000x reference)
//
#include <hip/hip_runtime.h>
#include <stdint.h>

#define EMBED 1024
#define HEAD  256
#define BATCH 8
#define SEQ   2048
#define NTOK  (BATCH*SEQ)

typedef __attribute__((ext_vector_type(8))) short  s16x8;
typedef __attribute__((ext_vector_type(4))) float  f32x4;
typedef __attribute__((ext_vector_type(4))) unsigned short u16x4;

__device__ __forceinline__ unsigned short f2bf(float f) {
  union { float f; uint32_t u; } v; v.f = f;
  return (unsigned short)((v.u + 0x7FFFu + ((v.u >> 16) & 1u)) >> 16);
}

__device__ __forceinline__ void gload_lds16(const void* g, void* l) {
  __builtin_amdgcn_global_load_lds((const __attribute__((address_space(1))) void*)g,
                                   (__attribute__((address_space(3))) void*)l, 16, 0, 0);
}

// ---------------- K0a: transpose weights -> Wt bf16 [3][256 h][1024 e] ----------------
__global__ __launch_bounds__(256) void wt_kernel(const float* __restrict__ Wq,
                                                 const float* __restrict__ Wk,
                                                 const float* __restrict__ Wv,
                                                 unsigned short* __restrict__ Wt) {
  int idx = blockIdx.x * 256 + threadIdx.x;
  int e  = idx & (EMBED - 1);
  int hw = idx >> 10;
  int w  = hw >> 8;
  int h  = hw & 255;
  const float* W = (w == 0) ? Wq : (w == 1) ? Wk : Wv;
  Wt[idx] = f2bf(W[(size_t)e * HEAD + h]);
}

// ---------------- K0b: x fp32 -> xb bf16 (once) ----------------
__global__ __launch_bounds__(256) void xprep_kernel(const float* __restrict__ x,
                                                    unsigned short* __restrict__ xb) {
  size_t i8 = ((size_t)blockIdx.x * 256 + threadIdx.x) * 8;
  f32x4 f0 = *(const f32x4*)(x + i8);
  f32x4 f1 = *(const f32x4*)(x + i8 + 4);
  u16x4 p0, p1;
  #pragma unroll
  for (int j = 0; j < 4; j++) { p0[j] = f2bf(f0[j]); p1[j] = f2bf(f1[j]); }
  *(u16x4*)(xb + i8)     = p0;
  *(u16x4*)(xb + i8 + 4) = p1;
}

// ---------------- K1: QKV projection GEMM (global_load_lds, linear LDS) ----------------
__global__ __launch_bounds__(256) void proj_kernel(const unsigned short* __restrict__ xb,
    const unsigned short* __restrict__ Wt,
    unsigned short* __restrict__ qo, unsigned short* __restrict__ ko,
    unsigned short* __restrict__ vt) {
  __shared__ unsigned short Al[128 * 64];   // linear, 16 KB
  __shared__ unsigned short Bl[128 * 64];   // linear, 16 KB
  const int tid  = threadIdx.x;
  const int lane = tid & 63;
  const int wid  = tid >> 6;
  const int wm = wid >> 1, wn = wid & 1;    // 2x2 waves, each 64x64 out
  const int m0 = blockIdx.x * 128;
  const int n0 = blockIdx.y * 128;
  const int w  = blockIdx.z;
  const unsigned short* Wtw = Wt + (size_t)w * 256 * EMBED;

  f32x4 acc[4][4] = {};

  for (int k0 = 0; k0 < EMBED; k0 += 64) {
    // 1024 chunks of 16B per tile: u = tid + 256*i; row = u>>3 (0..127), sc = u&7
    // lane's data belongs at linear elem u*8 = (i*2048 + wid*512) + lane*8
    // -> wave-uniform LDS base &Al[i*2048 + wid*512], global addr per-lane. OK.
    #pragma unroll
    for (int i = 0; i < 4; i++) {
      int u = tid + 256 * i;
      int row = u >> 3, sc = u & 7;
      gload_lds16(xb + (size_t)(m0 + row) * EMBED + k0 + sc * 8,
                  &Al[i * 2048 + wid * 512]);
    }
    #pragma unroll
    for (int i = 0; i < 4; i++) {
      int u = tid + 256 * i;
      int row = u >> 3, sc = u & 7;
      gload_lds16(Wtw + (size_t)(n0 + row) * EMBED + k0 + sc * 8,
                  &Bl[i * 2048 + wid * 512]);
    }
    __syncthreads();   // drains vmcnt incl. global_load_lds
    #pragma unroll
    for (int kk = 0; kk < 2; kk++) {
      s16x8 a[4], b[4];
      #pragma unroll
      for (int mi = 0; mi < 4; mi++) {
        int row = wm * 64 + mi * 16 + (lane & 15);
        a[mi] = *(const s16x8*)(&Al[row * 64 + kk * 32 + 8 * (lane >> 4)]);
      }
      #pragma unroll
      for (int ni = 0; ni < 4; ni++) {
        int row = wn * 64 + ni * 16 + (lane & 15);
        b[ni] = *(const s16x8*)(&Bl[row * 64 + kk * 32 + 8 * (lane >> 4)]);
      }
      #pragma unroll
      for (int mi = 0; mi < 4; mi++)
        #pragma unroll
        for (int ni = 0; ni < 4; ni++)
          acc[mi][ni] = __builtin_amdgcn_mfma_f32_16x16x32_bf16(a[mi], b[ni], acc[mi][ni], 0, 0, 0);
    }
    __syncthreads();   // LDS safe to overwrite
  }

  if (w < 2) {
    unsigned short* dst = (w == 0) ? qo : ko;
    #pragma unroll
    for (int mi = 0; mi < 4; mi++)
      #pragma unroll
      for (int r = 0; r < 4; r++) {
        int mrow = m0 + wm * 64 + mi * 16 + 4 * (lane >> 4) + r;
        #pragma unroll
        for (int ni = 0; ni < 4; ni++) {
          int col = n0 + wn * 64 + ni * 16 + (lane & 15);
          dst[(size_t)mrow * HEAD + col] = f2bf(acc[mi][ni][r]);
        }
      }
  } else {
    // V: write TRANSPOSED -> vt[h][token]
    #pragma unroll
    for (int mi = 0; mi < 4; mi++) {
      int base = m0 + wm * 64 + mi * 16 + 4 * (lane >> 4);
      #pragma unroll
      for (int ni = 0; ni < 4; ni++) {
        int col = n0 + wn * 64 + ni * 16 + (lane & 15);
        u16x4 pk;
        #pragma unroll
        for (int r = 0; r < 4; r++) pk[r] = f2bf(acc[mi][ni][r]);
        *(u16x4*)(vt + (size_t)col * NTOK + base) = pk;
      }
    }
  }
}

// ---------------- K2: causal flash attention, per-wave KV split ----------------
__global__ __launch_bounds__(256) void attn_kernel(const unsigned short* __restrict__ qb,
    const unsigned short* __restrict__ kb, const unsigned short* __restrict__ vt,
    float* __restrict__ out) {
  __shared__ unsigned short Pl[4][16 * 72];   // per-wave P round-trip
  __shared__ float mls[4][2][16];             // [wave][{m,l}][row]
  __shared__ float obuf[4][4][16][17];        // [srcwave][i][row][col], padded
  const int tid  = threadIdx.x;
  const int lane = tid & 63;
  const int wv   = tid >> 6;                  // 0..3 = KV chunk
  const int bid = blockIdx.x;
  const int b = bid & 7;                      // batch -> XCD affinity
  const int t = 127 - (bid >> 3);             // LPT: big causal ranges first
  const unsigned short* qB = qb + (size_t)b * SEQ * HEAD;
  const unsigned short* kB = kb + (size_t)b * SEQ * HEAD;
  const unsigned short* vB = vt + (size_t)b * SEQ;
  float* outB = out + (size_t)b * SEQ * HEAD;

  const int rowA = t * 16 + (lane & 15);
  const int rowD = t * 16 + 4 * (lane >> 4);

  s16x8 qf[8];
  #pragma unroll
  for (int kf = 0; kf < 8; kf++)
    qf[kf] = *(const s16x8*)(qB + (size_t)rowA * HEAD + kf * 32 + 8 * (lane >> 4));

  f32x4 o[16] = {};
  float m[4], lsum[4];
  #pragma unroll
  for (int r = 0; r < 4; r++) { m[r] = -1e30f; lsum[r] = 0.f; }

  const int nt64 = (t + 4) >> 2;              // ceil((t+1)*16 / 64)
  const int c    = (nt64 + 3) >> 2;           // tiles per wave

  for (int jj = 0; jj < c; jj++) {
    const int j = wv * c + jj;
    if (j >= nt64) break;
    // ---- S = Q K^T, K fragments straight from L2 ----
    f32x4 s[4] = {};
    #pragma unroll
    for (int n = 0; n < 4; n++) {
      int key = j * 64 + n * 16 + (lane & 15);
      #pragma unroll
      for (int kf = 0; kf < 8; kf++) {
        s16x8 kfr = *(const s16x8*)(kB + (size_t)key * HEAD + kf * 32 + 8 * (lane >> 4));
        s[n] = __builtin_amdgcn_mfma_f32_16x16x32_bf16(qf[kf], kfr, s[n], 0, 0, 0);
      }
    }
    const float scale = 0.0625f;
    float mt[4];
    #pragma unroll
    for (int r = 0; r < 4; r++) mt[r] = -1e30f;
    #pragma unroll
    for (int n = 0; n < 4; n++) {
      int key = j * 64 + n * 16 + (lane & 15);
      #pragma unroll
      for (int r = 0; r < 4; r++) {
        float sv = s[n][r] * scale;
        sv = (key > rowD + r) ? -1e30f : sv;
        s[n][r] = sv;
        mt[r] = fmaxf(mt[r], sv);
      }
    }
    #pragma unroll
    for (int r = 0; r < 4; r++) {
      #pragma unroll
      for (int xm = 1; xm < 16; xm <<= 1)
        mt[r] = fmaxf(mt[r], __shfl_xor(mt[r], xm));
      float mn = fmaxf(m[r], mt[r]);
      float al = __expf(m[r] - mn);
      m[r] = mn;
      lsum[r] *= al;
      #pragma unroll
      for (int ht = 0; ht < 16; ht++) o[ht][r] *= al;
    }
    float rs[4] = {0.f, 0.f, 0.f, 0.f};
    #pragma unroll
    for (int n = 0; n < 4; n++)
      #pragma unroll
      for (int r = 0; r < 4; r++) {
        float pv = __expf(s[n][r] - m[r]);
        rs[r] += pv;
        Pl[wv][(4 * (lane >> 4) + r) * 72 + n * 16 + (lane & 15)] = f2bf(pv);
      }
    #pragma unroll
    for (int r = 0; r < 4; r++) {
      #pragma unroll
      for (int xm = 1; xm < 16; xm <<= 1)
        rs[r] += __shfl_xor(rs[r], xm);
      lsum[r] += rs[r];
    }
    s16x8 pa[2];
    #pragma unroll
    for (int kf2 = 0; kf2 < 2; kf2++)
      pa[kf2] = *(const s16x8*)(&Pl[wv][(lane & 15) * 72 + kf2 * 32 + 8 * (lane >> 4)]);
    // ---- O += P V (V^T from L2) ----
    #pragma unroll
    for (int ht = 0; ht < 16; ht++) {
      int h = ht * 16 + (lane & 15);
      #pragma unroll
      for (int kf2 = 0; kf2 < 2; kf2++) {
        s16x8 vf = *(const s16x8*)(vB + (size_t)h * NTOK + j * 64 + kf2 * 32 + 8 * (lane >> 4));
        o[ht] = __builtin_amdgcn_mfma_f32_16x16x32_bf16(pa[kf2], vf, o[ht], 0, 0, 0);
      }
    }
  }

  // ---- merge partials across the 4 waves ----
  __syncthreads();
  if ((lane & 15) == 0) {
    #pragma unroll
    for (int r = 0; r < 4; r++) {
      int row = 4 * (lane >> 4) + r;
      mls[wv][0][row] = m[r];
      mls[wv][1][row] = lsum[r];
    }
  }
  __syncthreads();
  float Lv[4], aown[4];
  #pragma unroll
  for (int r = 0; r < 4; r++) {
    int row = 4 * (lane >> 4) + r;
    float mx = mls[0][0][row];
    #pragma unroll
    for (int w2 = 1; w2 < 4; w2++) mx = fmaxf(mx, mls[w2][0][row]);
    float L = 0.f;
    #pragma unroll
    for (int w2 = 0; w2 < 4; w2++)
      L += __expf(mls[w2][0][row] - mx) * mls[w2][1][row];
    Lv[r] = L;
    aown[r] = __expf(m[r] - mx);
  }
  for (int g = 0; g < 4; g++) {
    #pragma unroll
    for (int i = 0; i < 4; i++) {
      int ht = g * 4 + i;
      #pragma unroll
      for (int r = 0; r < 4; r++)
        obuf[wv][i][4 * (lane >> 4) + r][lane & 15] = o[ht][r] * aown[r];
    }
    __syncthreads();
    if (wv == g) {
      #pragma unroll
      for (int i = 0; i < 4; i++) {
        #pragma unroll
        for (int r = 0; r < 4; r++) {
          int row = 4 * (lane >> 4) + r;
          float v = obuf[0][i][row][lane & 15] + obuf[1][i][row][lane & 15]
                  + obuf[2][i][row][lane & 15] + obuf[3][i][row][lane & 15];
          outB[(size_t)(rowD + r) * HEAD + (g * 4 + i) * 16 + (lane & 15)] = v / Lv[r];
        }
      }
    }
    __syncthreads();
  }
}

extern "C" void kernel_launch(void* const* d_in, const int* in_sizes, int n_in,
                              void* d_out, int out_size, void* d_ws, size_t ws_size,
                              hipStream_t stream) {
  const float* x  = (const float*)d_in[0];
  const float* Wq = (const float*)d_in[1];
  const float* Wk = (const float*)d_in[2];
  const float* Wv = (const float*)d_in[3];
  float* out = (float*)d_out;

  unsigned short* ws = (unsigned short*)d_ws;
  unsigned short* qb = ws;                          // [16384][256] bf16
  unsigned short* kb = qb + (size_t)NTOK * HEAD;    // [16384][256]
  unsigned short* vt = kb + (size_t)NTOK * HEAD;    // TRANSPOSED [256 h][16384 tok]
  unsigned short* Wt = vt + (size_t)NTOK * HEAD;    // [3][256][1024] bf16
  unsigned short* xb = Wt + (size_t)3 * HEAD * EMBED; // [16384][1024] bf16
  // total ws use: 24.75 + 1.5 + 32 = ~58.25 MB

  hipLaunchKernelGGL(wt_kernel, dim3(3 * 256 * EMBED / 256), dim3(256), 0, stream,
                     Wq, Wk, Wv, Wt);
  hipLaunchKernelGGL(xprep_kernel, dim3(NTOK * EMBED / (256 * 8)), dim3(256), 0, stream,
                     x, xb);
  hipLaunchKernelGGL(proj_kernel, dim3(128, 2, 3), dim3(256), 0, stream,
                     xb, Wt, qb, kb, vt);
  hipLaunchKernelGGL(attn_kernel, dim3(1024), dim3(256), 0, stream,
                     qb, kb, vt, out);
}